// Round 22
// baseline (602.586 us; speedup 1.0000x reference)
//
#include <hip/hip_runtime.h>
#include <stdint.h>

// LinearBin: out = x @ sign(W)^T + bias   (B=131072, IN=OUT=512, fp32)
// v22: v21 (127.8us) x NS=4 strips/block. Continuous DMA ring across strips;
//      per-strip stores are fire-and-forget in the vmcnt FIFO and the next
//      strip's first 3 chunk-waits are vmcnt(34) (=2 DMA + 32 stores) so
//      stores drain under compute -- no generation-boundary write convoy.
//      Last strip issues clamped dummy DMAs to keep the ladder uniform.
//      Grid 1024 (2 blocks/CU, 2 generations). Rest is v21-verbatim.

#define BATCH   131072
#define IN_F    512
#define OUT_F   512
#define BM      32
#define NS      4             // strips per block
#define NCH     8             // K-chunks of 64 floats per strip
#define BUFB    8192          // bytes per ring buffer (32 rows x 256B)

using f32x4  = __attribute__((ext_vector_type(4))) float;
using f32x16 = __attribute__((ext_vector_type(16))) float;
using short8 = __attribute__((ext_vector_type(8))) short;
using u32    = uint32_t;
using u64    = unsigned long long;

// ---------------- prep: pack sign bits (verified v20) ----------------
__global__ void prep_wbits(const float* __restrict__ W, u32* __restrict__ wp) {
    int t = blockIdx.x * blockDim.x + threadIdx.x;  // 1024 threads
    int l  = t & 63;
    int nf = t >> 6;
    const float* row = W + (size_t)(nf * 32 + (l & 31)) * IN_F + ((l >> 5) << 3);
#pragma unroll
    for (int q = 0; q < 8; ++q) {
        u32 word = 0;
#pragma unroll
        for (int b = 0; b < 4; ++b) {
            const float* p = row + (q * 4 + b) * 16;
            u32 by = 0;
#pragma unroll
            for (int j = 0; j < 8; ++j)
                by |= (p[j] >= 0.0f ? 0u : 1u) << j;
            word |= by << (8 * b);
        }
        wp[(size_t)t * 8 + q] = word;
    }
}

// bits (low 8 of bb) -> short8 of bf16 +/-1 (multiply-spread, verified v20)
__device__ __forceinline__ short8 expB(u32 bb) {
    const u64 MUL = 0x1000200040008000ull;
    const u64 MSK = 0x8000800080008000ull;
    const u64 ONE = 0x3F803F803F803F80ull;
    u64 lo = ((u64)(bb & 0xFu) * MUL) & MSK;
    u64 hi = ((u64)((bb >> 4) & 0xFu) * MUL) & MSK;
    union { u64 d[2]; short8 v; } pk;
    pk.d[0] = ONE | lo;
    pk.d[1] = ONE | hi;
    return pk.v;
}

// ---------------- GEMM ----------------
__global__ __launch_bounds__(512, 4) void gemm_bin(
    const float* __restrict__ X, const u32* __restrict__ WP,
    const float* __restrict__ bias, float* __restrict__ out) {

    // ring of 4 fp32 chunks: [32 rows][256B], 16B slots XOR-swizzled by row&15
    __shared__ __align__(16) char smem[4 * BUFB];   // 32KB -> 2 blocks/CU

    const int tid  = threadIdx.x;
    const int lane = tid & 63;
    const int wv   = tid >> 6;              // 0..7 -> 64-col strip
    const size_t m0 = (size_t)blockIdx.x * (BM * NS);   // grid = 1024
    const int col0 = wv * 64;

    // ---- B-bit panel (FIFO-oldest): 16 u32 per lane ----
    const u32* wpp = WP + (((size_t)(wv * 2) * 64 + lane) << 3);
    uint4 a0 = *(const uint4*)(wpp);
    uint4 a1 = *(const uint4*)(wpp + 4);
    uint4 b0 = *(const uint4*)(wpp + 512);
    uint4 b1 = *(const uint4*)(wpp + 516);
    __builtin_amdgcn_sched_barrier(0);

    const float bv0 = bias[col0 + (lane & 31)];
    const float bv1 = bias[col0 + 32 + (lane & 31)];
    __builtin_amdgcn_sched_barrier(0);

    const u32 w0[8] = {a0.x, a0.y, a0.z, a0.w, a1.x, a1.y, a1.z, a1.w};
    const u32 w1[8] = {b0.x, b0.y, b0.z, b0.w, b1.x, b1.y, b1.z, b1.w};

    // ---- DMA geometry: 1 x 16B per thread per chunk (512 thr = 8KB) ----
    const int dr   = wv * 4 + (lane >> 4);
    const int ds4  = ((lane & 15) ^ (dr & 15)) << 2;
    const float* src_base = X + (m0 + dr) * IN_F + ds4;

#define ISSUE_DMA(srcp_, ck_, buf_)                                            \
    {                                                                          \
        char* b_ = smem + (buf_) * BUFB + wv * 1024;                           \
        __builtin_amdgcn_global_load_lds(                                      \
            (const __attribute__((address_space(1))) void*)((srcp_) + (ck_) * 64),\
            (__attribute__((address_space(3))) void*)(b_), 16, 0, 0);          \
    }

    // ---- prologue: 3 chunks of strip 0 in flight ----
    ISSUE_DMA(src_base, 0, 0);
    ISSUE_DMA(src_base, 1, 1);
    ISSUE_DMA(src_base, 2, 2);
    __builtin_amdgcn_sched_barrier(0);

    // ---- A-frag geometry (16-slot swizzle, verified 0-conflict) ----
    const int arow = (lane & 31) * 256;
    const int aq32 = (lane >> 5) << 5;
    const int aswz = (lane & 15) << 4;
    const int c     = lane & 31;
    const int rbase = (lane >> 5) << 2;

#pragma unroll 1
    for (int s = 0; s < NS; ++s) {
        const float* srcs = src_base + (size_t)s * (BM * IN_F);
        // next-strip source; clamped to a valid dummy for the last strip
        const float* srcn = (s + 1 < NS) ? srcs + (BM * IN_F) : src_base;

        f32x16 acc[2];
#pragma unroll
        for (int r = 0; r < 16; ++r) { acc[0][r] = bv0; acc[1][r] = bv1; }

#pragma unroll
        for (int ck = 0; ck < NCH; ++ck) {
            // expand this chunk's 8 B-frags (DMA-wait shadow)
            short8 bf[4][2];
#pragma unroll
            for (int k4 = 0; k4 < 4; ++k4) {
                const int kt = ck * 4 + k4;
                bf[k4][0] = expB(w0[kt >> 2] >> ((kt & 3) * 8));
                bf[k4][1] = expB(w1[kt >> 2] >> ((kt & 3) * 8));
            }
            __builtin_amdgcn_sched_barrier(0);
            // wait: first 3 chunks of strips s>0 carry 32 stores in the FIFO
            if (s > 0 && ck < 3) asm volatile("s_waitcnt vmcnt(34)" ::: "memory");
            else                 asm volatile("s_waitcnt vmcnt(2)"  ::: "memory");
            __builtin_amdgcn_sched_barrier(0);
            __builtin_amdgcn_s_barrier();
            __builtin_amdgcn_sched_barrier(0);
            // issue 3-ahead: ck<=4 same strip; ck>=5 next strip (or dummy)
            if (ck <= 4) ISSUE_DMA(srcs, ck + 3, (ck + 3) & 3)
            else         ISSUE_DMA(srcn, ck - 5, (ck + 3) & 3)
            __builtin_amdgcn_sched_barrier(0);

            const char* ab = smem + (ck & 3) * BUFB;
#pragma unroll
            for (int k4 = 0; k4 < 4; ++k4) {
                const int blo = ((k4 << 6) + aq32) ^ aswz;
                f32x4 lo = *(const f32x4*)(ab + arow + blo);
                f32x4 hi = *(const f32x4*)(ab + arow + (blo ^ 16));
                u32 c0, c1, c2, c3;
                asm("v_cvt_pk_bf16_f32 %0, %1, %2" : "=v"(c0) : "v"(lo[0]), "v"(lo[1]));
                asm("v_cvt_pk_bf16_f32 %0, %1, %2" : "=v"(c1) : "v"(lo[2]), "v"(lo[3]));
                asm("v_cvt_pk_bf16_f32 %0, %1, %2" : "=v"(c2) : "v"(hi[0]), "v"(hi[1]));
                asm("v_cvt_pk_bf16_f32 %0, %1, %2" : "=v"(c3) : "v"(hi[2]), "v"(hi[3]));
                union { u32 w[4]; short8 v; } pk;
                pk.w[0] = c0; pk.w[1] = c1; pk.w[2] = c2; pk.w[3] = c3;
                __builtin_amdgcn_s_setprio(1);
                acc[0] = __builtin_amdgcn_mfma_f32_32x32x16_bf16(pk.v, bf[k4][0], acc[0], 0, 0, 0);
                acc[1] = __builtin_amdgcn_mfma_f32_32x32x16_bf16(pk.v, bf[k4][1], acc[1], 0, 0, 0);
                __builtin_amdgcn_s_setprio(0);
            }
        }

        // ---- strip epilogue: fire-and-forget stores (32 per thread) ----
        {
            const size_t ms = m0 + (size_t)s * BM;
#pragma unroll
            for (int fn = 0; fn < 2; ++fn)
#pragma unroll
                for (int r = 0; r < 16; ++r) {
                    const int row = (r & 3) + 8 * (r >> 2) + rbase;
                    out[(ms + row) * OUT_F + col0 + fn * 32 + c] = acc[fn][r];
                }
        }
        __builtin_amdgcn_sched_barrier(0);
    }
#undef ISSUE_DMA
}

extern "C" void kernel_launch(void* const* d_in, const int* in_sizes, int n_in,
                              void* d_out, int out_size, void* d_ws, size_t ws_size,
                              hipStream_t stream) {
    const float* X    = (const float*)d_in[0];
    const float* W    = (const float*)d_in[1];
    const float* bias = (const float*)d_in[2];
    float* o          = (float*)d_out;
    u32* wp           = (u32*)d_ws;   // 32KB packed sign bits

    hipLaunchKernelGGL(prep_wbits, dim3(4), dim3(256), 0, stream, W, wp);
    hipLaunchKernelGGL(gemm_bin, dim3(BATCH / (BM * NS)), dim3(512), 0, stream,
                       X, wp, bias, o);
}

// Round 23
// 437.885 us; speedup vs baseline: 1.3761x; 1.3761x over previous
//
#include <hip/hip_runtime.h>
#include <stdint.h>

// LinearBin: out = x @ sign(W)^T + bias   (B=131072, IN=OUT=512, fp32)
// v23: v21 (127.8us) at BM=64 -- halves the chip-total expB VALU (the v21
//      binding term: VALUBusy 50%) by halving block count. Wave tile 64x64
//      (rg=2), chunk = 64rows x 64fp32 = 16KB, ring 4x16KB = 64KB, still
//      2 blocks/CU. DMA 2 instr/wave/chunk, pure-DMA FIFO lead 3
//      (vmcnt 4/2/0). Bit-packed register B + expB + 16-slot swizzle
//      verbatim from v21. Straight-line (no runtime loops -- v22 lesson).

#define BATCH   131072
#define IN_F    512
#define OUT_F   512
#define BM      64
#define NCH     8             // K-chunks of 64 floats (4 mfma k-steps each)
#define BUFB    16384         // bytes per ring buffer (64 rows x 256B)

using f32x4  = __attribute__((ext_vector_type(4))) float;
using f32x16 = __attribute__((ext_vector_type(16))) float;
using short8 = __attribute__((ext_vector_type(8))) short;
using u32    = uint32_t;
using u64    = unsigned long long;

// ---------------- prep: pack sign bits (verified v20/v21) ----------------
// wp[(nf*64+l)*8 + q], byte b (kt=4q+b), bit j =
//   (W[nf*32+(l&31)][kt*16 + (l>>5)*8 + j] < 0)
__global__ void prep_wbits(const float* __restrict__ W, u32* __restrict__ wp) {
    int t = blockIdx.x * blockDim.x + threadIdx.x;  // 1024 threads
    int l  = t & 63;
    int nf = t >> 6;
    const float* row = W + (size_t)(nf * 32 + (l & 31)) * IN_F + ((l >> 5) << 3);
#pragma unroll
    for (int q = 0; q < 8; ++q) {
        u32 word = 0;
#pragma unroll
        for (int b = 0; b < 4; ++b) {
            const float* p = row + (q * 4 + b) * 16;
            u32 by = 0;
#pragma unroll
            for (int j = 0; j < 8; ++j)
                by |= (p[j] >= 0.0f ? 0u : 1u) << j;
            word |= by << (8 * b);
        }
        wp[(size_t)t * 8 + q] = word;
    }
}

// bits (low 8 of bb) -> short8 of bf16 +/-1 (multiply-spread, verified v20)
__device__ __forceinline__ short8 expB(u32 bb) {
    const u64 MUL = 0x1000200040008000ull;
    const u64 MSK = 0x8000800080008000ull;
    const u64 ONE = 0x3F803F803F803F80ull;
    u64 lo = ((u64)(bb & 0xFu) * MUL) & MSK;
    u64 hi = ((u64)((bb >> 4) & 0xFu) * MUL) & MSK;
    union { u64 d[2]; short8 v; } pk;
    pk.d[0] = ONE | lo;
    pk.d[1] = ONE | hi;
    return pk.v;
}

// ---------------- GEMM ----------------
__global__ __launch_bounds__(512, 4) void gemm_bin(
    const float* __restrict__ X, const u32* __restrict__ WP,
    const float* __restrict__ bias, float* __restrict__ out) {

    // ring of 4 fp32 chunks: [64 rows][256B], 16B slots XOR-swizzled by row&15
    __shared__ __align__(16) char smem[4 * BUFB];   // 64KB -> 2 blocks/CU

    const int tid  = threadIdx.x;
    const int lane = tid & 63;
    const int wv   = tid >> 6;              // 0..7 -> 64-col strip
    const int m0   = blockIdx.x * BM;       // grid = 2048
    const int col0 = wv * 64;

    // ---- B-bit panel (FIFO-oldest): 16 u32 per lane ----
    const u32* wpp = WP + (((size_t)(wv * 2) * 64 + lane) << 3);
    uint4 a0 = *(const uint4*)(wpp);
    uint4 a1 = *(const uint4*)(wpp + 4);
    uint4 b0 = *(const uint4*)(wpp + 512);   // nf+1 = +64*8 u32
    uint4 b1 = *(const uint4*)(wpp + 516);
    __builtin_amdgcn_sched_barrier(0);

    // ---- bias -> acc init ----
    f32x16 acc[2][2];
#pragma unroll
    for (int fn = 0; fn < 2; ++fn) {
        const float bv = bias[col0 + fn * 32 + (lane & 31)];
#pragma unroll
        for (int rg = 0; rg < 2; ++rg)
#pragma unroll
            for (int r = 0; r < 16; ++r) acc[rg][fn][r] = bv;
    }
    __builtin_amdgcn_sched_barrier(0);

    const u32 w0[8] = {a0.x, a0.y, a0.z, a0.w, a1.x, a1.y, a1.z, a1.w};
    const u32 w1[8] = {b0.x, b0.y, b0.z, b0.w, b1.x, b1.y, b1.z, b1.w};

    // ---- DMA geometry: 2 x 16B per thread per chunk (512 thr = 16KB) ----
    // rows dr (0..31) and dr+32; pre-swizzled source; (dr+32)&15 == dr&15.
    const int dr   = wv * 4 + (lane >> 4);
    const int ds4  = ((lane & 15) ^ (dr & 15)) << 2;
    const float* src0 = X + (size_t)(m0 + dr) * IN_F + ds4;
    const float* src1 = src0 + (size_t)32 * IN_F;

#define ISSUE_DMA(ck_)                                                         \
    {                                                                          \
        char* b_ = smem + ((ck_) & 3) * BUFB + wv * 1024;                      \
        __builtin_amdgcn_global_load_lds(                                      \
            (const __attribute__((address_space(1))) void*)(src0 + (ck_) * 64),\
            (__attribute__((address_space(3))) void*)(b_), 16, 0, 0);          \
        __builtin_amdgcn_global_load_lds(                                      \
            (const __attribute__((address_space(1))) void*)(src1 + (ck_) * 64),\
            (__attribute__((address_space(3))) void*)(b_ + 8192), 16, 0, 0);   \
    }

    // ---- prologue: 3 chunks of DMA in flight ----
    ISSUE_DMA(0);
    ISSUE_DMA(1);
    ISSUE_DMA(2);
    __builtin_amdgcn_sched_barrier(0);

    // ---- A-frag geometry (16-slot swizzle, verified 0-conflict) ----
    // row = rg*32 + (lane&31); row&15 == lane&15 for both rg.
    const int arow = (lane & 31) * 256;
    const int aq32 = (lane >> 5) << 5;
    const int aswz = (lane & 15) << 4;

#pragma unroll
    for (int ck = 0; ck < NCH; ++ck) {
        // expand this chunk's 8 B-frags from register bits (DMA-wait shadow)
        short8 bf[4][2];
#pragma unroll
        for (int k4 = 0; k4 < 4; ++k4) {
            const int kt = ck * 4 + k4;
            bf[k4][0] = expB(w0[kt >> 2] >> ((kt & 3) * 8));
            bf[k4][1] = expB(w1[kt >> 2] >> ((kt & 3) * 8));
        }
        __builtin_amdgcn_sched_barrier(0);
        // retire exactly DMA(ck) (2 instrs); ck+1, ck+2 stay in flight
        if (ck < NCH - 2)       asm volatile("s_waitcnt vmcnt(4)" ::: "memory");
        else if (ck == NCH - 2) asm volatile("s_waitcnt vmcnt(2)" ::: "memory");
        else                    asm volatile("s_waitcnt vmcnt(0)" ::: "memory");
        __builtin_amdgcn_sched_barrier(0);
        __builtin_amdgcn_s_barrier();
        __builtin_amdgcn_sched_barrier(0);
        if (ck + 3 < NCH) ISSUE_DMA(ck + 3);  // buf (ck-1)&3 freed by barrier

        const char* ab = smem + (ck & 3) * BUFB;
#pragma unroll
        for (int k4 = 0; k4 < 4; ++k4) {
            const int blo = ((k4 << 6) + aq32) ^ aswz;
            short8 afr[2];
#pragma unroll
            for (int rg = 0; rg < 2; ++rg) {
                const char* p_ = ab + rg * 8192 + arow;
                f32x4 lo = *(const f32x4*)(p_ + blo);
                f32x4 hi = *(const f32x4*)(p_ + (blo ^ 16));
                u32 c0, c1, c2, c3;
                asm("v_cvt_pk_bf16_f32 %0, %1, %2" : "=v"(c0) : "v"(lo[0]), "v"(lo[1]));
                asm("v_cvt_pk_bf16_f32 %0, %1, %2" : "=v"(c1) : "v"(lo[2]), "v"(lo[3]));
                asm("v_cvt_pk_bf16_f32 %0, %1, %2" : "=v"(c2) : "v"(hi[0]), "v"(hi[1]));
                asm("v_cvt_pk_bf16_f32 %0, %1, %2" : "=v"(c3) : "v"(hi[2]), "v"(hi[3]));
                union { u32 w[4]; short8 v; } pk;
                pk.w[0] = c0; pk.w[1] = c1; pk.w[2] = c2; pk.w[3] = c3;
                afr[rg] = pk.v;
            }
            __builtin_amdgcn_s_setprio(1);
#pragma unroll
            for (int rg = 0; rg < 2; ++rg)
#pragma unroll
                for (int fn = 0; fn < 2; ++fn)
                    acc[rg][fn] = __builtin_amdgcn_mfma_f32_32x32x16_bf16(
                        afr[rg], bf[k4][fn], acc[rg][fn], 0, 0, 0);
            __builtin_amdgcn_s_setprio(0);
        }
    }
#undef ISSUE_DMA

    // ---- epilogue: direct stores (bias already in acc) ----
    // C/D: col = lane&31, row = (r&3) + 8*(r>>2) + 4*(lane>>5)
    const int c     = lane & 31;
    const int rbase = (lane >> 5) << 2;
#pragma unroll
    for (int rg = 0; rg < 2; ++rg)
#pragma unroll
        for (int fn = 0; fn < 2; ++fn)
#pragma unroll
            for (int r = 0; r < 16; ++r) {
                const int row = rg * 32 + (r & 3) + 8 * (r >> 2) + rbase;
                out[(size_t)(m0 + row) * OUT_F + col0 + fn * 32 + c] =
                    acc[rg][fn][r];
            }
}

extern "C" void kernel_launch(void* const* d_in, const int* in_sizes, int n_in,
                              void* d_out, int out_size, void* d_ws, size_t ws_size,
                              hipStream_t stream) {
    const float* X    = (const float*)d_in[0];
    const float* W    = (const float*)d_in[1];
    const float* bias = (const float*)d_in[2];
    float* o          = (float*)d_out;
    u32* wp           = (u32*)d_ws;   // 32KB packed sign bits

    hipLaunchKernelGGL(prep_wbits, dim3(4), dim3(256), 0, stream, W, wp);
    hipLaunchKernelGGL(gemm_bin, dim3(BATCH / BM), dim3(512), 0, stream,
                       X, wp, bias, o);
}

// Round 24
// 122.026 us; speedup vs baseline: 4.9382x; 3.5885x over previous
//
#include <hip/hip_runtime.h>
#include <stdint.h>

// LinearBin: out = x @ sign(W)^T + bias   (B=131072, IN=OUT=512, fp32)
// v24: v23 (BM=64, halved expB redundancy) on a register diet to stop the
//      v23 spill: bf expanded inline per-k4 (16 live regs, not 32) and afr
//      computed per-rg and consumed immediately (8 regs, not 16). Live set
//      ~124 <= 128 cap at 4 waves/SIMD. All else v23-verbatim: 4x16KB fp32
//      ring, 2-instr DMA, vmcnt(4/2/0) FIFO ladder, 16-slot swizzle,
//      bit-packed register B, bias-in-acc, direct epilogue.

#define BATCH   131072
#define IN_F    512
#define OUT_F   512
#define BM      64
#define NCH     8             // K-chunks of 64 floats (4 mfma k-steps each)
#define BUFB    16384         // bytes per ring buffer (64 rows x 256B)

using f32x4  = __attribute__((ext_vector_type(4))) float;
using f32x16 = __attribute__((ext_vector_type(16))) float;
using short8 = __attribute__((ext_vector_type(8))) short;
using u32    = uint32_t;
using u64    = unsigned long long;

// ---------------- prep: pack sign bits (verified v20/v21) ----------------
// wp[(nf*64+l)*8 + q], byte b (kt=4q+b), bit j =
//   (W[nf*32+(l&31)][kt*16 + (l>>5)*8 + j] < 0)
__global__ void prep_wbits(const float* __restrict__ W, u32* __restrict__ wp) {
    int t = blockIdx.x * blockDim.x + threadIdx.x;  // 1024 threads
    int l  = t & 63;
    int nf = t >> 6;
    const float* row = W + (size_t)(nf * 32 + (l & 31)) * IN_F + ((l >> 5) << 3);
#pragma unroll
    for (int q = 0; q < 8; ++q) {
        u32 word = 0;
#pragma unroll
        for (int b = 0; b < 4; ++b) {
            const float* p = row + (q * 4 + b) * 16;
            u32 by = 0;
#pragma unroll
            for (int j = 0; j < 8; ++j)
                by |= (p[j] >= 0.0f ? 0u : 1u) << j;
            word |= by << (8 * b);
        }
        wp[(size_t)t * 8 + q] = word;
    }
}

// bits (low 8 of bb) -> short8 of bf16 +/-1 (multiply-spread, verified v20)
__device__ __forceinline__ short8 expB(u32 bb) {
    const u64 MUL = 0x1000200040008000ull;
    const u64 MSK = 0x8000800080008000ull;
    const u64 ONE = 0x3F803F803F803F80ull;
    u64 lo = ((u64)(bb & 0xFu) * MUL) & MSK;
    u64 hi = ((u64)((bb >> 4) & 0xFu) * MUL) & MSK;
    union { u64 d[2]; short8 v; } pk;
    pk.d[0] = ONE | lo;
    pk.d[1] = ONE | hi;
    return pk.v;
}

// ---------------- GEMM ----------------
__global__ __launch_bounds__(512, 4) void gemm_bin(
    const float* __restrict__ X, const u32* __restrict__ WP,
    const float* __restrict__ bias, float* __restrict__ out) {

    // ring of 4 fp32 chunks: [64 rows][256B], 16B slots XOR-swizzled by row&15
    __shared__ __align__(16) char smem[4 * BUFB];   // 64KB -> 2 blocks/CU

    const int tid  = threadIdx.x;
    const int lane = tid & 63;
    const int wv   = tid >> 6;              // 0..7 -> 64-col strip
    const int m0   = blockIdx.x * BM;       // grid = 2048
    const int col0 = wv * 64;

    // ---- B-bit panel (FIFO-oldest): 16 u32 per lane ----
    const u32* wpp = WP + (((size_t)(wv * 2) * 64 + lane) << 3);
    uint4 a0 = *(const uint4*)(wpp);
    uint4 a1 = *(const uint4*)(wpp + 4);
    uint4 b0 = *(const uint4*)(wpp + 512);   // nf+1 = +64*8 u32
    uint4 b1 = *(const uint4*)(wpp + 516);
    __builtin_amdgcn_sched_barrier(0);

    // ---- bias -> acc init ----
    f32x16 acc[2][2];
#pragma unroll
    for (int fn = 0; fn < 2; ++fn) {
        const float bv = bias[col0 + fn * 32 + (lane & 31)];
#pragma unroll
        for (int rg = 0; rg < 2; ++rg)
#pragma unroll
            for (int r = 0; r < 16; ++r) acc[rg][fn][r] = bv;
    }
    __builtin_amdgcn_sched_barrier(0);

    const u32 w0[8] = {a0.x, a0.y, a0.z, a0.w, a1.x, a1.y, a1.z, a1.w};
    const u32 w1[8] = {b0.x, b0.y, b0.z, b0.w, b1.x, b1.y, b1.z, b1.w};

    // ---- DMA geometry: 2 x 16B per thread per chunk (512 thr = 16KB) ----
    const int dr   = wv * 4 + (lane >> 4);
    const int ds4  = ((lane & 15) ^ (dr & 15)) << 2;
    const float* src0 = X + (size_t)(m0 + dr) * IN_F + ds4;
    const float* src1 = src0 + (size_t)32 * IN_F;   // (dr+32)&15 == dr&15

#define ISSUE_DMA(ck_)                                                         \
    {                                                                          \
        char* b_ = smem + ((ck_) & 3) * BUFB + wv * 1024;                      \
        __builtin_amdgcn_global_load_lds(                                      \
            (const __attribute__((address_space(1))) void*)(src0 + (ck_) * 64),\
            (__attribute__((address_space(3))) void*)(b_), 16, 0, 0);          \
        __builtin_amdgcn_global_load_lds(                                      \
            (const __attribute__((address_space(1))) void*)(src1 + (ck_) * 64),\
            (__attribute__((address_space(3))) void*)(b_ + 8192), 16, 0, 0);   \
    }

    // ---- prologue: 3 chunks of DMA in flight ----
    ISSUE_DMA(0);
    ISSUE_DMA(1);
    ISSUE_DMA(2);
    __builtin_amdgcn_sched_barrier(0);

    // ---- A-frag geometry (16-slot swizzle, verified 0-conflict) ----
    const int arow = (lane & 31) * 256;
    const int aq32 = (lane >> 5) << 5;
    const int aswz = (lane & 15) << 4;

#pragma unroll
    for (int ck = 0; ck < NCH; ++ck) {
        // retire exactly DMA(ck) (2 instrs); ck+1, ck+2 stay in flight
        if (ck < NCH - 2)       asm volatile("s_waitcnt vmcnt(4)" ::: "memory");
        else if (ck == NCH - 2) asm volatile("s_waitcnt vmcnt(2)" ::: "memory");
        else                    asm volatile("s_waitcnt vmcnt(0)" ::: "memory");
        __builtin_amdgcn_sched_barrier(0);
        __builtin_amdgcn_s_barrier();
        __builtin_amdgcn_sched_barrier(0);
        if (ck + 3 < NCH) ISSUE_DMA(ck + 3);  // buf (ck-1)&3 freed by barrier

        const char* ab = smem + (ck & 3) * BUFB;
#pragma unroll
        for (int k4 = 0; k4 < 4; ++k4) {
            const int kt = ck * 4 + k4;
            // inline B expansion: only 2 frags (16 regs) live at a time
            short8 b0f = expB(w0[kt >> 2] >> ((kt & 3) * 8));
            short8 b1f = expB(w1[kt >> 2] >> ((kt & 3) * 8));
            const int blo = ((k4 << 6) + aq32) ^ aswz;
#pragma unroll
            for (int rg = 0; rg < 2; ++rg) {
                const char* p_ = ab + rg * 8192 + arow;
                f32x4 lo = *(const f32x4*)(p_ + blo);
                f32x4 hi = *(const f32x4*)(p_ + (blo ^ 16));
                u32 c0, c1, c2, c3;
                asm("v_cvt_pk_bf16_f32 %0, %1, %2" : "=v"(c0) : "v"(lo[0]), "v"(lo[1]));
                asm("v_cvt_pk_bf16_f32 %0, %1, %2" : "=v"(c1) : "v"(lo[2]), "v"(lo[3]));
                asm("v_cvt_pk_bf16_f32 %0, %1, %2" : "=v"(c2) : "v"(hi[0]), "v"(hi[1]));
                asm("v_cvt_pk_bf16_f32 %0, %1, %2" : "=v"(c3) : "v"(hi[2]), "v"(hi[3]));
                union { u32 w[4]; short8 v; } pk;
                pk.w[0] = c0; pk.w[1] = c1; pk.w[2] = c2; pk.w[3] = c3;
                __builtin_amdgcn_s_setprio(1);
                acc[rg][0] = __builtin_amdgcn_mfma_f32_32x32x16_bf16(
                    pk.v, b0f, acc[rg][0], 0, 0, 0);
                acc[rg][1] = __builtin_amdgcn_mfma_f32_32x32x16_bf16(
                    pk.v, b1f, acc[rg][1], 0, 0, 0);
                __builtin_amdgcn_s_setprio(0);
            }
        }
    }
#undef ISSUE_DMA

    // ---- epilogue: direct stores (bias already in acc) ----
    // C/D: col = lane&31, row = (r&3) + 8*(r>>2) + 4*(lane>>5)
    const int c     = lane & 31;
    const int rbase = (lane >> 5) << 2;
#pragma unroll
    for (int rg = 0; rg < 2; ++rg)
#pragma unroll
        for (int fn = 0; fn < 2; ++fn)
#pragma unroll
            for (int r = 0; r < 16; ++r) {
                const int row = rg * 32 + (r & 3) + 8 * (r >> 2) + rbase;
                out[(size_t)(m0 + row) * OUT_F + col0 + fn * 32 + c] =
                    acc[rg][fn][r];
            }
}

extern "C" void kernel_launch(void* const* d_in, const int* in_sizes, int n_in,
                              void* d_out, int out_size, void* d_ws, size_t ws_size,
                              hipStream_t stream) {
    const float* X    = (const float*)d_in[0];
    const float* W    = (const float*)d_in[1];
    const float* bias = (const float*)d_in[2];
    float* o          = (float*)d_out;
    u32* wp           = (u32*)d_ws;   // 32KB packed sign bits

    hipLaunchKernelGGL(prep_wbits, dim3(4), dim3(256), 0, stream, W, wp);
    hipLaunchKernelGGL(gemm_bin, dim3(BATCH / BM), dim3(512), 0, stream,
                       X, wp, bias, o);
}

// Round 25
// 120.655 us; speedup vs baseline: 4.9943x; 1.0114x over previous
//
#include <hip/hip_runtime.h>
#include <stdint.h>

// LinearBin: out = x @ sign(W)^T + bias   (B=131072, IN=OUT=512, fp32)
// v25: v24 (122.0us) + lockstep deskew. (1) per-wave k4 rotation: wave wv
//      runs k4 order (k4+wv)&3 so the 8 waves exit each barrier into
//      different LDS offsets / stall phases (cross-wave latency hiding);
//      (2) the 4 ds_reads of each k4 are issued BEFORE the expB so ~40cy
//      of expansion VALU covers read latency in-wave; (3) setprio dropped
//      (T5: null-to-negative on barrier-synced GEMM). All else v24-verbatim.

#define BATCH   131072
#define IN_F    512
#define OUT_F   512
#define BM      64
#define NCH     8             // K-chunks of 64 floats (4 mfma k-steps each)
#define BUFB    16384         // bytes per ring buffer (64 rows x 256B)

using f32x4  = __attribute__((ext_vector_type(4))) float;
using f32x16 = __attribute__((ext_vector_type(16))) float;
using short8 = __attribute__((ext_vector_type(8))) short;
using u32    = uint32_t;
using u64    = unsigned long long;

// ---------------- prep: pack sign bits (verified v20/v21) ----------------
// wp[(nf*64+l)*8 + q], byte b (kt=4q+b), bit j =
//   (W[nf*32+(l&31)][kt*16 + (l>>5)*8 + j] < 0)
__global__ void prep_wbits(const float* __restrict__ W, u32* __restrict__ wp) {
    int t = blockIdx.x * blockDim.x + threadIdx.x;  // 1024 threads
    int l  = t & 63;
    int nf = t >> 6;
    const float* row = W + (size_t)(nf * 32 + (l & 31)) * IN_F + ((l >> 5) << 3);
#pragma unroll
    for (int q = 0; q < 8; ++q) {
        u32 word = 0;
#pragma unroll
        for (int b = 0; b < 4; ++b) {
            const float* p = row + (q * 4 + b) * 16;
            u32 by = 0;
#pragma unroll
            for (int j = 0; j < 8; ++j)
                by |= (p[j] >= 0.0f ? 0u : 1u) << j;
            word |= by << (8 * b);
        }
        wp[(size_t)t * 8 + q] = word;
    }
}

// bits (low 8 of bb) -> short8 of bf16 +/-1 (multiply-spread, verified v20)
__device__ __forceinline__ short8 expB(u32 bb) {
    const u64 MUL = 0x1000200040008000ull;
    const u64 MSK = 0x8000800080008000ull;
    const u64 ONE = 0x3F803F803F803F80ull;
    u64 lo = ((u64)(bb & 0xFu) * MUL) & MSK;
    u64 hi = ((u64)((bb >> 4) & 0xFu) * MUL) & MSK;
    union { u64 d[2]; short8 v; } pk;
    pk.d[0] = ONE | lo;
    pk.d[1] = ONE | hi;
    return pk.v;
}

// ---------------- GEMM ----------------
__global__ __launch_bounds__(512, 4) void gemm_bin(
    const float* __restrict__ X, const u32* __restrict__ WP,
    const float* __restrict__ bias, float* __restrict__ out) {

    // ring of 4 fp32 chunks: [64 rows][256B], 16B slots XOR-swizzled by row&15
    __shared__ __align__(16) char smem[4 * BUFB];   // 64KB -> 2 blocks/CU

    const int tid  = threadIdx.x;
    const int lane = tid & 63;
    const int wv   = tid >> 6;              // 0..7 -> 64-col strip
    const int m0   = blockIdx.x * BM;       // grid = 2048
    const int col0 = wv * 64;

    // ---- B-bit panel (FIFO-oldest): 16 u32 per lane ----
    const u32* wpp = WP + (((size_t)(wv * 2) * 64 + lane) << 3);
    uint4 a0 = *(const uint4*)(wpp);
    uint4 a1 = *(const uint4*)(wpp + 4);
    uint4 b0 = *(const uint4*)(wpp + 512);   // nf+1 = +64*8 u32
    uint4 b1 = *(const uint4*)(wpp + 516);
    __builtin_amdgcn_sched_barrier(0);

    // ---- bias -> acc init ----
    f32x16 acc[2][2];
#pragma unroll
    for (int fn = 0; fn < 2; ++fn) {
        const float bv = bias[col0 + fn * 32 + (lane & 31)];
#pragma unroll
        for (int rg = 0; rg < 2; ++rg)
#pragma unroll
            for (int r = 0; r < 16; ++r) acc[rg][fn][r] = bv;
    }
    __builtin_amdgcn_sched_barrier(0);

    const u32 w0[8] = {a0.x, a0.y, a0.z, a0.w, a1.x, a1.y, a1.z, a1.w};
    const u32 w1[8] = {b0.x, b0.y, b0.z, b0.w, b1.x, b1.y, b1.z, b1.w};

    // ---- DMA geometry: 2 x 16B per thread per chunk (512 thr = 16KB) ----
    const int dr   = wv * 4 + (lane >> 4);
    const int ds4  = ((lane & 15) ^ (dr & 15)) << 2;
    const float* src0 = X + (size_t)(m0 + dr) * IN_F + ds4;
    const float* src1 = src0 + (size_t)32 * IN_F;   // (dr+32)&15 == dr&15

#define ISSUE_DMA(ck_)                                                         \
    {                                                                          \
        char* b_ = smem + ((ck_) & 3) * BUFB + wv * 1024;                      \
        __builtin_amdgcn_global_load_lds(                                      \
            (const __attribute__((address_space(1))) void*)(src0 + (ck_) * 64),\
            (__attribute__((address_space(3))) void*)(b_), 16, 0, 0);          \
        __builtin_amdgcn_global_load_lds(                                      \
            (const __attribute__((address_space(1))) void*)(src1 + (ck_) * 64),\
            (__attribute__((address_space(3))) void*)(b_ + 8192), 16, 0, 0);   \
    }

    // ---- prologue: 3 chunks of DMA in flight ----
    ISSUE_DMA(0);
    ISSUE_DMA(1);
    ISSUE_DMA(2);
    __builtin_amdgcn_sched_barrier(0);

    // ---- A-frag geometry (16-slot swizzle, verified 0-conflict) ----
    const int arow = (lane & 31) * 256;
    const int aq32 = (lane >> 5) << 5;
    const int aswz = (lane & 15) << 4;

#pragma unroll
    for (int ck = 0; ck < NCH; ++ck) {
        // retire exactly DMA(ck) (2 instrs); ck+1, ck+2 stay in flight
        if (ck < NCH - 2)       asm volatile("s_waitcnt vmcnt(4)" ::: "memory");
        else if (ck == NCH - 2) asm volatile("s_waitcnt vmcnt(2)" ::: "memory");
        else                    asm volatile("s_waitcnt vmcnt(0)" ::: "memory");
        __builtin_amdgcn_sched_barrier(0);
        __builtin_amdgcn_s_barrier();
        __builtin_amdgcn_sched_barrier(0);
        if (ck + 3 < NCH) ISSUE_DMA(ck + 3);  // buf (ck-1)&3 freed by barrier

        const char* ab = smem + (ck & 3) * BUFB;
#pragma unroll
        for (int k4 = 0; k4 < 4; ++k4) {
            // per-wave rotation: waves leave the barrier into different
            // k-offsets -> stall phases deskew, cross-wave hiding works.
            const int kk = (k4 + wv) & 3;
            const int kt = ck * 4 + kk;
            const int blo = ((kk << 6) + aq32) ^ aswz;
            // hoist all 4 ds_reads ahead of the expansion VALU
            f32x4 lo0 = *(const f32x4*)(ab + arow + blo);
            f32x4 hi0 = *(const f32x4*)(ab + arow + (blo ^ 16));
            f32x4 lo1 = *(const f32x4*)(ab + 8192 + arow + blo);
            f32x4 hi1 = *(const f32x4*)(ab + 8192 + arow + (blo ^ 16));
            short8 b0f = expB(w0[kt >> 2] >> ((kt & 3) * 8));
            short8 b1f = expB(w1[kt >> 2] >> ((kt & 3) * 8));
            u32 c0, c1, c2, c3;
            asm("v_cvt_pk_bf16_f32 %0, %1, %2" : "=v"(c0) : "v"(lo0[0]), "v"(lo0[1]));
            asm("v_cvt_pk_bf16_f32 %0, %1, %2" : "=v"(c1) : "v"(lo0[2]), "v"(lo0[3]));
            asm("v_cvt_pk_bf16_f32 %0, %1, %2" : "=v"(c2) : "v"(hi0[0]), "v"(hi0[1]));
            asm("v_cvt_pk_bf16_f32 %0, %1, %2" : "=v"(c3) : "v"(hi0[2]), "v"(hi0[3]));
            union { u32 w[4]; short8 v; } pka;
            pka.w[0] = c0; pka.w[1] = c1; pka.w[2] = c2; pka.w[3] = c3;
            acc[0][0] = __builtin_amdgcn_mfma_f32_32x32x16_bf16(
                pka.v, b0f, acc[0][0], 0, 0, 0);
            acc[0][1] = __builtin_amdgcn_mfma_f32_32x32x16_bf16(
                pka.v, b1f, acc[0][1], 0, 0, 0);
            asm("v_cvt_pk_bf16_f32 %0, %1, %2" : "=v"(c0) : "v"(lo1[0]), "v"(lo1[1]));
            asm("v_cvt_pk_bf16_f32 %0, %1, %2" : "=v"(c1) : "v"(lo1[2]), "v"(lo1[3]));
            asm("v_cvt_pk_bf16_f32 %0, %1, %2" : "=v"(c2) : "v"(hi1[0]), "v"(hi1[1]));
            asm("v_cvt_pk_bf16_f32 %0, %1, %2" : "=v"(c3) : "v"(hi1[2]), "v"(hi1[3]));
            union { u32 w[4]; short8 v; } pkb;
            pkb.w[0] = c0; pkb.w[1] = c1; pkb.w[2] = c2; pkb.w[3] = c3;
            acc[1][0] = __builtin_amdgcn_mfma_f32_32x32x16_bf16(
                pkb.v, b0f, acc[1][0], 0, 0, 0);
            acc[1][1] = __builtin_amdgcn_mfma_f32_32x32x16_bf16(
                pkb.v, b1f, acc[1][1], 0, 0, 0);
        }
    }
#undef ISSUE_DMA

    // ---- epilogue: direct stores (bias already in acc) ----
    // C/D: col = lane&31, row = (r&3) + 8*(r>>2) + 4*(lane>>5)
    const int c     = lane & 31;
    const int rbase = (lane >> 5) << 2;
#pragma unroll
    for (int rg = 0; rg < 2; ++rg)
#pragma unroll
        for (int fn = 0; fn < 2; ++fn)
#pragma unroll
            for (int r = 0; r < 16; ++r) {
                const int row = rg * 32 + (r & 3) + 8 * (r >> 2) + rbase;
                out[(size_t)(m0 + row) * OUT_F + col0 + fn * 32 + c] =
                    acc[rg][fn][r];
            }
}

extern "C" void kernel_launch(void* const* d_in, const int* in_sizes, int n_in,
                              void* d_out, int out_size, void* d_ws, size_t ws_size,
                              hipStream_t stream) {
    const float* X    = (const float*)d_in[0];
    const float* W    = (const float*)d_in[1];
    const float* bias = (const float*)d_in[2];
    float* o          = (float*)d_out;
    u32* wp           = (u32*)d_ws;   // 32KB packed sign bits

    hipLaunchKernelGGL(prep_wbits, dim3(4), dim3(256), 0, stream, W, wp);
    hipLaunchKernelGGL(gemm_bin, dim3(BATCH / BM), dim3(512), 0, stream,
                       X, wp, bias, o);
}

// Round 26
// 119.647 us; speedup vs baseline: 5.0364x; 1.0084x over previous
//
#include <hip/hip_runtime.h>
#include <stdint.h>

// LinearBin: out = x @ sign(W)^T + bias   (B=131072, IN=OUT=512, fp32)
// v26: v25 (120.7us) with DMA ring 4->5 buffers (80KB, still 2 blocks/CU)
//      and lead 3->4 chunks: 33% more slack against HBM/L3-miss jitter at
//      zero register cost. Steady wait vmcnt(6); D(ck+4) issued post-barrier
//      into the buffer that barrier freed. All else v25-verbatim
//      (bit-packed register B, expB, deskewed k4, hoisted ds_reads,
//      16-slot swizzle, bias-in-acc, direct epilogue).

#define BATCH   131072
#define IN_F    512
#define OUT_F   512
#define BM      64
#define NCH     8             // K-chunks of 64 floats (4 mfma k-steps each)
#define NBUF    5
#define BUFB    16384         // bytes per ring buffer (64 rows x 256B)

using f32x4  = __attribute__((ext_vector_type(4))) float;
using f32x16 = __attribute__((ext_vector_type(16))) float;
using short8 = __attribute__((ext_vector_type(8))) short;
using u32    = uint32_t;
using u64    = unsigned long long;

// ---------------- prep: pack sign bits (verified v20/v21) ----------------
// wp[(nf*64+l)*8 + q], byte b (kt=4q+b), bit j =
//   (W[nf*32+(l&31)][kt*16 + (l>>5)*8 + j] < 0)
__global__ void prep_wbits(const float* __restrict__ W, u32* __restrict__ wp) {
    int t = blockIdx.x * blockDim.x + threadIdx.x;  // 1024 threads
    int l  = t & 63;
    int nf = t >> 6;
    const float* row = W + (size_t)(nf * 32 + (l & 31)) * IN_F + ((l >> 5) << 3);
#pragma unroll
    for (int q = 0; q < 8; ++q) {
        u32 word = 0;
#pragma unroll
        for (int b = 0; b < 4; ++b) {
            const float* p = row + (q * 4 + b) * 16;
            u32 by = 0;
#pragma unroll
            for (int j = 0; j < 8; ++j)
                by |= (p[j] >= 0.0f ? 0u : 1u) << j;
            word |= by << (8 * b);
        }
        wp[(size_t)t * 8 + q] = word;
    }
}

// bits (low 8 of bb) -> short8 of bf16 +/-1 (multiply-spread, verified v20)
__device__ __forceinline__ short8 expB(u32 bb) {
    const u64 MUL = 0x1000200040008000ull;
    const u64 MSK = 0x8000800080008000ull;
    const u64 ONE = 0x3F803F803F803F80ull;
    u64 lo = ((u64)(bb & 0xFu) * MUL) & MSK;
    u64 hi = ((u64)((bb >> 4) & 0xFu) * MUL) & MSK;
    union { u64 d[2]; short8 v; } pk;
    pk.d[0] = ONE | lo;
    pk.d[1] = ONE | hi;
    return pk.v;
}

// ---------------- GEMM ----------------
__global__ __launch_bounds__(512, 4) void gemm_bin(
    const float* __restrict__ X, const u32* __restrict__ WP,
    const float* __restrict__ bias, float* __restrict__ out) {

    // ring of 5 fp32 chunks: [64 rows][256B], 16B slots XOR-swizzled by row&15
    __shared__ __align__(16) char smem[NBUF * BUFB];   // 80KB -> 2 blocks/CU

    const int tid  = threadIdx.x;
    const int lane = tid & 63;
    const int wv   = tid >> 6;              // 0..7 -> 64-col strip
    const int m0   = blockIdx.x * BM;       // grid = 2048
    const int col0 = wv * 64;

    // ---- B-bit panel (FIFO-oldest): 16 u32 per lane ----
    const u32* wpp = WP + (((size_t)(wv * 2) * 64 + lane) << 3);
    uint4 a0 = *(const uint4*)(wpp);
    uint4 a1 = *(const uint4*)(wpp + 4);
    uint4 b0 = *(const uint4*)(wpp + 512);   // nf+1 = +64*8 u32
    uint4 b1 = *(const uint4*)(wpp + 516);
    __builtin_amdgcn_sched_barrier(0);

    // ---- bias -> acc init ----
    f32x16 acc[2][2];
#pragma unroll
    for (int fn = 0; fn < 2; ++fn) {
        const float bv = bias[col0 + fn * 32 + (lane & 31)];
#pragma unroll
        for (int rg = 0; rg < 2; ++rg)
#pragma unroll
            for (int r = 0; r < 16; ++r) acc[rg][fn][r] = bv;
    }
    __builtin_amdgcn_sched_barrier(0);

    const u32 w0[8] = {a0.x, a0.y, a0.z, a0.w, a1.x, a1.y, a1.z, a1.w};
    const u32 w1[8] = {b0.x, b0.y, b0.z, b0.w, b1.x, b1.y, b1.z, b1.w};

    // ---- DMA geometry: 2 x 16B per thread per chunk (512 thr = 16KB) ----
    const int dr   = wv * 4 + (lane >> 4);
    const int ds4  = ((lane & 15) ^ (dr & 15)) << 2;
    const float* src0 = X + (size_t)(m0 + dr) * IN_F + ds4;
    const float* src1 = src0 + (size_t)32 * IN_F;   // (dr+32)&15 == dr&15

#define ISSUE_DMA(ck_)                                                         \
    {                                                                          \
        char* b_ = smem + ((ck_) % NBUF) * BUFB + wv * 1024;                   \
        __builtin_amdgcn_global_load_lds(                                      \
            (const __attribute__((address_space(1))) void*)(src0 + (ck_) * 64),\
            (__attribute__((address_space(3))) void*)(b_), 16, 0, 0);          \
        __builtin_amdgcn_global_load_lds(                                      \
            (const __attribute__((address_space(1))) void*)(src1 + (ck_) * 64),\
            (__attribute__((address_space(3))) void*)(b_ + 8192), 16, 0, 0);   \
    }

    // ---- prologue: 4 chunks of DMA in flight ----
    ISSUE_DMA(0);
    ISSUE_DMA(1);
    ISSUE_DMA(2);
    ISSUE_DMA(3);
    __builtin_amdgcn_sched_barrier(0);

    // ---- A-frag geometry (16-slot swizzle, verified 0-conflict) ----
    const int arow = (lane & 31) * 256;
    const int aq32 = (lane >> 5) << 5;
    const int aswz = (lane & 15) << 4;

#pragma unroll
    for (int ck = 0; ck < NCH; ++ck) {
        // retire exactly DMA(ck): outstanding = 2*(min(NCH-1,ck+3)-ck+1)
        if (ck < NCH - 3)       asm volatile("s_waitcnt vmcnt(6)" ::: "memory");
        else if (ck == NCH - 3) asm volatile("s_waitcnt vmcnt(4)" ::: "memory");
        else if (ck == NCH - 2) asm volatile("s_waitcnt vmcnt(2)" ::: "memory");
        else                    asm volatile("s_waitcnt vmcnt(0)" ::: "memory");
        __builtin_amdgcn_sched_barrier(0);
        __builtin_amdgcn_s_barrier();
        __builtin_amdgcn_sched_barrier(0);
        if (ck + 4 < NCH) ISSUE_DMA(ck + 4);  // buf (ck-1)%5 freed by barrier

        const char* ab = smem + (ck % NBUF) * BUFB;
#pragma unroll
        for (int k4 = 0; k4 < 4; ++k4) {
            // per-wave k4 rotation (v25): deskew wave stall phases
            const int kk = (k4 + wv) & 3;
            const int kt = ck * 4 + kk;
            const int blo = ((kk << 6) + aq32) ^ aswz;
            f32x4 lo0 = *(const f32x4*)(ab + arow + blo);
            f32x4 hi0 = *(const f32x4*)(ab + arow + (blo ^ 16));
            f32x4 lo1 = *(const f32x4*)(ab + 8192 + arow + blo);
            f32x4 hi1 = *(const f32x4*)(ab + 8192 + arow + (blo ^ 16));
            short8 b0f = expB(w0[kt >> 2] >> ((kt & 3) * 8));
            short8 b1f = expB(w1[kt >> 2] >> ((kt & 3) * 8));
            u32 c0, c1, c2, c3;
            asm("v_cvt_pk_bf16_f32 %0, %1, %2" : "=v"(c0) : "v"(lo0[0]), "v"(lo0[1]));
            asm("v_cvt_pk_bf16_f32 %0, %1, %2" : "=v"(c1) : "v"(lo0[2]), "v"(lo0[3]));
            asm("v_cvt_pk_bf16_f32 %0, %1, %2" : "=v"(c2) : "v"(hi0[0]), "v"(hi0[1]));
            asm("v_cvt_pk_bf16_f32 %0, %1, %2" : "=v"(c3) : "v"(hi0[2]), "v"(hi0[3]));
            union { u32 w[4]; short8 v; } pka;
            pka.w[0] = c0; pka.w[1] = c1; pka.w[2] = c2; pka.w[3] = c3;
            acc[0][0] = __builtin_amdgcn_mfma_f32_32x32x16_bf16(
                pka.v, b0f, acc[0][0], 0, 0, 0);
            acc[0][1] = __builtin_amdgcn_mfma_f32_32x32x16_bf16(
                pka.v, b1f, acc[0][1], 0, 0, 0);
            asm("v_cvt_pk_bf16_f32 %0, %1, %2" : "=v"(c0) : "v"(lo1[0]), "v"(lo1[1]));
            asm("v_cvt_pk_bf16_f32 %0, %1, %2" : "=v"(c1) : "v"(lo1[2]), "v"(lo1[3]));
            asm("v_cvt_pk_bf16_f32 %0, %1, %2" : "=v"(c2) : "v"(hi1[0]), "v"(hi1[1]));
            asm("v_cvt_pk_bf16_f32 %0, %1, %2" : "=v"(c3) : "v"(hi1[2]), "v"(hi1[3]));
            union { u32 w[4]; short8 v; } pkb;
            pkb.w[0] = c0; pkb.w[1] = c1; pkb.w[2] = c2; pkb.w[3] = c3;
            acc[1][0] = __builtin_amdgcn_mfma_f32_32x32x16_bf16(
                pkb.v, b0f, acc[1][0], 0, 0, 0);
            acc[1][1] = __builtin_amdgcn_mfma_f32_32x32x16_bf16(
                pkb.v, b1f, acc[1][1], 0, 0, 0);
        }
    }
#undef ISSUE_DMA

    // ---- epilogue: direct stores (bias already in acc) ----
    // C/D: col = lane&31, row = (r&3) + 8*(r>>2) + 4*(lane>>5)
    const int c     = lane & 31;
    const int rbase = (lane >> 5) << 2;
#pragma unroll
    for (int rg = 0; rg < 2; ++rg)
#pragma unroll
        for (int fn = 0; fn < 2; ++fn)
#pragma unroll
            for (int r = 0; r < 16; ++r) {
                const int row = rg * 32 + (r & 3) + 8 * (r >> 2) + rbase;
                out[(size_t)(m0 + row) * OUT_F + col0 + fn * 32 + c] =
                    acc[rg][fn][r];
            }
}

extern "C" void kernel_launch(void* const* d_in, const int* in_sizes, int n_in,
                              void* d_out, int out_size, void* d_ws, size_t ws_size,
                              hipStream_t stream) {
    const float* X    = (const float*)d_in[0];
    const float* W    = (const float*)d_in[1];
    const float* bias = (const float*)d_in[2];
    float* o          = (float*)d_out;
    u32* wp           = (u32*)d_ws;   // 32KB packed sign bits

    hipLaunchKernelGGL(prep_wbits, dim3(4), dim3(256), 0, stream, W, wp);
    hipLaunchKernelGGL(gemm_bin, dim3(BATCH / BM), dim3(512), 0, stream,
                       X, wp, bias, o);
}